// Round 5
// baseline (534.328 us; speedup 1.0000x reference)
//
#include <hip/hip_runtime.h>

// DEChannelPool: 6 soft-morphology branches + per-channel BN + 1x1 conv + BN + ReLU.
// Trick 1: exp(beta*(w±x)) = exp(beta*w)*exp(±beta*x): 2 exps per input pixel.
// Trick 2: BN+conv fold to alpha*log2(S) + const; const cancels in final scalar BN.
// R4: side-split, channel-looped reduce with plain stores (no atomics).
// R5: (a) k_stats merges both sides (one tile load -> two planes; halves FETCH and
//     loader VALU; inlines wexp); (b) k_reduce channel-splits NS in {4,2,1} gated on
//     ws_size (slab partials + k_fsum), 64x16 tiles / 8-row strips (25% fewer LDS
//     reads per output), inlines alpha; (c) kernel count 6 -> 5/4 (launch gaps were
//     ~60 us of the R4 wall time).

#define BETA 15.0f
#define MSHIFT 25.0f
#define INV_BETA (1.0f/15.0f)
#define LN2 0.6931471805599453f
#define EPSB 1e-5f
#define Hn 192
#define Wn 192
#define HWn (192*192)
#define N1 (8*192*192)
#define SFLOOR 1e-37f

// ---- stats kernel geometry: 64r x 32c tile, 8-row strips, 256 thr, BOTH sides ----
#define STDH 70
#define STW 38
#define STSTR 39            // 8*39 % 32 = 24 -> 2-way strip aliasing (free)
#define STNL (STDH*STW)     // 2660

// workspace layout (float offsets)
#define WS_SUM   0
#define WS_SQS   384
#define WS_SCAL  768
#define WS_YE    772
#define WS_YD    (772 + 294912)
#define WS_SLAB  (772 + 2*294912)   // NS*2 side-groups x 8 b x HWn

// Register-rotating stencil over one plane. Each b32 read feeds up to 3 of the H
// output accumulators. All offsets literal after unroll.
template<int D, int H, int STR>
__device__ __forceinline__ void sweepT(const float* __restrict__ P,
                                       int py0, int px,
                                       const float* __restrict__ wgp,
                                       float* __restrict__ S) {
    float W[9];
#pragma unroll
    for (int k2 = 0; k2 < 9; ++k2) W[k2] = wgp[k2];
#pragma unroll
    for (int k = 0; k < H; ++k) S[k] = 0.f;
    const float* base = P + (py0 - D + 3) * STR + (px - D);
#pragma unroll
    for (int r = 0; r < H + 2 * D; ++r) {
        float va = base[r * STR];
        float vb = base[r * STR + D];
        float vc = base[r * STR + 2 * D];
#pragma unroll
        for (int i = 0; i < 3; ++i) {
            int k = r - i * D;            // output row fed by input row r via weight-row i
            if (k >= 0 && k < H) {
                S[k] = fmaf(W[i*3+0], va, S[k]);
                S[k] = fmaf(W[i*3+1], vb, S[k]);
                S[k] = fmaf(W[i*3+2], vc, S[k]);
            }
        }
    }
}

__device__ __forceinline__ void red2(float a, float b2, int lane, float* rs, float* rq) {
#pragma unroll
    for (int off = 32; off; off >>= 1) {
        a  += __shfl_down(a, off, 64);
        b2 += __shfl_down(b2, off, 64);
    }
    if (lane == 0) { *rs = a; *rq = b2; }
}

// grid (18 tiles, 512 b*c), 256 threads. One tile load feeds BOTH side planes.
__global__ __launch_bounds__(256, 7) void k_stats(
    const float* __restrict__ x, const float* __restrict__ we,
    const float* __restrict__ wd,
    float* __restrict__ sum, float* __restrict__ sqs) {
    __shared__ float EX[STDH * STSTR], EY[STDH * STSTR];
    __shared__ float wgl[54];
    __shared__ float redS[4][6], redQ[4][6];
    const int tid = threadIdx.x;
    const int p = blockIdx.y;            // b*64 + c
    const int c = p & 63;
    const int t = blockIdx.x;
    const int h0 = (t / 6) * 64, w0 = (t % 6) * 32;

    if (tid < 54) {                       // inline wexp: this block's 54 weights
        int side = tid / 27, rem = tid - side * 27;   // br*9 + k
        const float* wsrc = side ? wd : we;
        wgl[tid] = __expf(BETA * wsrc[(rem / 9) * 576 + c * 9 + (rem % 9)]);
    }
    const float* xp = x + (size_t)p * HWn;
    {
        int r = tid / STW, cc = tid - r * STW;
        for (int l = tid; l < STNL; l += 256) {
            int gh = h0 - 3 + r, gw = w0 - 3 + cc;
            float v = 0.f;
            if ((unsigned)gh < (unsigned)Hn && (unsigned)gw < (unsigned)Wn)
                v = xp[gh * Wn + gw];
            float bx = BETA * v;          // OOB/pad: v=0 -> exp(-M) both sides, correct
            EX[r * STSTR + cc] = __expf(-bx - MSHIFT);
            EY[r * STSTR + cc] = __expf( bx - MSHIFT);
            r += 6; cc += 28;             // 256 = 6*38 + 28
            if (cc >= STW) { cc -= STW; ++r; }
        }
    }
    __syncthreads();

    const int px = (tid & 31) + 3;
    const int py0 = (tid >> 5) * 8;
    const int lane = tid & 63, wv = tid >> 6;
    const float LI = LN2 * INV_BETA, MI = MSHIFT * INV_BETA;

#define DO_BR_STATS(D, SLOT, PL, AL, AM, WOFS) { \
    float S[8]; \
    sweepT<D, 8, STSTR>(PL, py0, px, &wgl[WOFS], S); \
    float sv = 0.f, qv = 0.f; \
    _Pragma("unroll") \
    for (int k = 0; k < 8; ++k) { \
        float m = fmaf(__log2f(fmaxf(S[k], SFLOOR)), AL, AM); \
        sv += m; qv = fmaf(m, m, qv); \
    } \
    red2(sv, qv, lane, &redS[wv][SLOT], &redQ[wv][SLOT]); }

    DO_BR_STATS(1, 0, EX, -LI, -MI, 0)
    DO_BR_STATS(2, 1, EX, -LI, -MI, 9)
    DO_BR_STATS(3, 2, EX, -LI, -MI, 18)
    DO_BR_STATS(1, 3, EY,  LI,  MI, 27)
    DO_BR_STATS(2, 4, EY,  LI,  MI, 36)
    DO_BR_STATS(3, 5, EY,  LI,  MI, 45)

    __syncthreads();
    if (tid < 6)
        atomicAdd(&sum[tid * 64 + c],
                  redS[0][tid] + redS[1][tid] + redS[2][tid] + redS[3][tid]);
    else if (tid < 12) {
        int v = tid - 6;
        atomicAdd(&sqs[v * 64 + c],
                  redQ[0][v] + redQ[1][v] + redQ[2][v] + redQ[3][v]);
    }
}

// grid ((192/(8*TH))*12, 8, 2*NS), 128 threads. Block sweeps NC=64/NS channels of one
// side over a (8*TH x 16) tile; NS>1 stores partials to its slab; NS==1 stores final
// ye/yd + scalar BN stats. alpha computed in-block (kills k_alpha); weights exp'd
// in-block into LDS (kills k_wexp).
template<int NS, int TH>
__global__ __launch_bounds__(128, 8) void k_reduce(
    const float* __restrict__ x,
    const float* __restrict__ we, const float* __restrict__ wd,
    const float* __restrict__ sum, const float* __restrict__ sqs,
    const float* __restrict__ bn_ge, const float* __restrict__ bn_gd,
    const float* __restrict__ conve, const float* __restrict__ convd,
    float* __restrict__ ye, float* __restrict__ yd,
    float* __restrict__ slab, float* __restrict__ scal) {
    constexpr int TILE_H = 8 * TH;
    constexpr int DH = TILE_H + 6;
    constexpr int NL = DH * 22;
    constexpr int NC = 64 / NS;
    constexpr int NITER = (NL + 127) / 128;
    __shared__ float E[DH * 26];          // 8*TH strips: TH*26 % 32 -> 2-way (free)
    __shared__ float wgl[NC * 27];
    __shared__ float al[192];
    __shared__ float redA[2][2];
    const int tid = threadIdx.x;
    const int t = blockIdx.x;
    const int b = blockIdx.y;
    const int z = blockIdx.z;
    const int side = z / NS, grp = z - side * NS;
    const int c0 = grp * NC;
    const int tr = t / 12, tc = t - tr * 12;
    const int h0 = tr * TILE_H, w0 = tc * 16;
    const int px = (tid & 15) + 3;
    const int py0 = (tid >> 4) * TH;
    const float sb = side ? BETA : -BETA;
    const float* xb = x + (size_t)b * 64 * HWn;

    {   // inline wexp for this block's channels
        const float* wsrc = side ? wd : we;
        for (int l = tid; l < NC * 27; l += 128) {
            int br = l / (NC * 9), r2 = l - br * NC * 9;
            int cl = r2 / 9, k = r2 - cl * 9;
            wgl[l] = __expf(BETA * wsrc[br * 576 + (c0 + cl) * 9 + k]);
        }
    }
    {   // inline alpha for this side (192 channels)
        for (int l = tid; l < 192; l += 128) {
            float mean = sum[side * 192 + l] * (1.0f / N1);
            float var  = sqs[side * 192 + l] * (1.0f / N1) - mean * mean;
            float inv  = rsqrtf(fmaxf(var, 0.f) + EPSB);
            float g  = side ? bn_gd[l] : bn_ge[l];
            float cw = side ? convd[l] : conve[l];
            float sgn = side ? 1.f : -1.f;
            al[l] = sgn * cw * g * inv * INV_BETA * LN2;
        }
    }

    float acc[TH];
#pragma unroll
    for (int k = 0; k < TH; ++k) acc[k] = 0.f;
    float L[NITER];

    // prologue: prefetch channel c0 into registers
    {
        const float* xp = xb + (size_t)c0 * HWn;
        int r = tid / 22, cc = tid - r * 22;
#pragma unroll
        for (int i = 0; i < NITER; ++i) {
            int l = tid + i * 128;
            float v = 0.f;
            if (l < NL) {
                int gh = h0 - 3 + r, gw = w0 - 3 + cc;
                if ((unsigned)gh < (unsigned)Hn && (unsigned)gw < (unsigned)Wn)
                    v = xp[gh * Wn + gw];
            }
            L[i] = v;
            r += 5; cc += 18;             // 128 = 5*22 + 18
            if (cc >= 22) { cc -= 22; ++r; }
        }
    }

    for (int ci = 0; ci < NC; ++ci) {
        __syncthreads();                  // E free (and 1st iter: wgl/al visible)
        {   // write phase (OOB loaded as 0 -> exp(-M), correct)
            int r = tid / 22, cc = tid - r * 22;
#pragma unroll
            for (int i = 0; i < NITER; ++i) {
                int l = tid + i * 128;
                if (l < NL) E[r * 26 + cc] = __expf(sb * L[i] - MSHIFT);
                r += 5; cc += 18;
                if (cc >= 22) { cc -= 22; ++r; }
            }
        }
        __syncthreads();
        if (ci < NC - 1) {                // prefetch next channel (overlaps sweeps)
            const float* xp = xb + (size_t)(c0 + ci + 1) * HWn;
            int r = tid / 22, cc = tid - r * 22;
#pragma unroll
            for (int i = 0; i < NITER; ++i) {
                int l = tid + i * 128;
                float v = 0.f;
                if (l < NL) {
                    int gh = h0 - 3 + r, gw = w0 - 3 + cc;
                    if ((unsigned)gh < (unsigned)Hn && (unsigned)gw < (unsigned)Wn)
                        v = xp[gh * Wn + gw];
                }
                L[i] = v;
                r += 5; cc += 18;
                if (cc >= 22) { cc -= 22; ++r; }
            }
        }
#define DO_BR_ACC(D, BR) { \
        float S[TH]; \
        sweepT<D, TH, 26>(E, py0, px, &wgl[((BR) * NC + ci) * 9], S); \
        const float a_ = al[(BR) * 64 + c0 + ci]; \
        _Pragma("unroll") \
        for (int k = 0; k < TH; ++k) \
            acc[k] = fmaf(a_, __log2f(fmaxf(S[k], SFLOOR)), acc[k]); }

        DO_BR_ACC(1, 0)
        DO_BR_ACC(2, 1)
        DO_BR_ACC(3, 2)
    }

    if constexpr (NS == 1) {
        float* yo = side ? yd : ye;
#pragma unroll
        for (int k = 0; k < TH; ++k)
            yo[b * HWn + (h0 + py0 + k) * Wn + (w0 + px - 3)] = acc[k];
        float s = 0.f, q = 0.f;
#pragma unroll
        for (int k = 0; k < TH; ++k) { s += acc[k]; q = fmaf(acc[k], acc[k], q); }
        const int lane = tid & 63, wv = tid >> 6;
#pragma unroll
        for (int off = 32; off; off >>= 1) {
            s += __shfl_down(s, off, 64);
            q += __shfl_down(q, off, 64);
        }
        if (lane == 0) { redA[wv][0] = s; redA[wv][1] = q; }
        __syncthreads();
        if (tid == 0) {
            atomicAdd(&scal[side * 2 + 0], redA[0][0] + redA[1][0]);
            atomicAdd(&scal[side * 2 + 1], redA[0][1] + redA[1][1]);
        }
    } else {
        float* po = slab + ((size_t)(side * NS + grp) * 8 + b) * HWn;
#pragma unroll
        for (int k = 0; k < TH; ++k)
            po[(h0 + py0 + k) * Wn + (w0 + px - 3)] = acc[k];
    }
}

// NS>1 path: sum the NS chunk partials per pixel -> ye/yd + scalar BN stats.
template<int NS>
__global__ __launch_bounds__(256) void k_fsum(
    const float* __restrict__ slab,
    float* __restrict__ ye, float* __restrict__ yd, float* __restrict__ scal) {
    int i = blockIdx.x * 256 + threadIdx.x;   // < 294912
    int b = i / HWn, rem = i - b * HWn;
    float e = 0.f, d = 0.f;
#pragma unroll
    for (int g = 0; g < NS; ++g) {
        e += slab[((size_t)(g) * 8 + b) * HWn + rem];
        d += slab[((size_t)(NS + g) * 8 + b) * HWn + rem];
    }
    ye[i] = e; yd[i] = d;
    float v[4] = {e, e * e, d, d * d};
    __shared__ float red[4][4];
    int lane = threadIdx.x & 63, wv = threadIdx.x >> 6;
#pragma unroll
    for (int k = 0; k < 4; ++k) {
        float tv = v[k];
#pragma unroll
        for (int off = 32; off; off >>= 1) tv += __shfl_down(tv, off, 64);
        if (lane == 0) red[wv][k] = tv;
    }
    __syncthreads();
    if (threadIdx.x < 4)
        atomicAdd(&scal[threadIdx.x],
                  red[0][threadIdx.x] + red[1][threadIdx.x] + red[2][threadIdx.x] + red[3][threadIdx.x]);
}

__global__ __launch_bounds__(256) void k_final(
    const float* __restrict__ ye, const float* __restrict__ yd,
    const float* __restrict__ scal,
    const float* __restrict__ g_e, const float* __restrict__ b_e,
    const float* __restrict__ g_d, const float* __restrict__ b_d,
    float* __restrict__ out) {
    int i = blockIdx.x * 256 + threadIdx.x;  // < 294912
    float me_ = scal[0] * (1.0f / N1);
    float ve  = scal[1] * (1.0f / N1) - me_ * me_;
    float ie  = rsqrtf(fmaxf(ve, 0.f) + EPSB);
    float md_ = scal[2] * (1.0f / N1);
    float vd  = scal[3] * (1.0f / N1) - md_ * md_;
    float idv = rsqrtf(fmaxf(vd, 0.f) + EPSB);
    float ge = g_e[0], be = b_e[0];
    float gd = g_d[0], bd = b_d[0];
    int b = i / HWn, rem = i - b * HWn;
    float oe = fmaxf(ge * (ye[i] - me_) * ie + be, 0.f);
    float od = fmaxf(gd * (yd[i] - md_) * idv + bd, 0.f);
    out[(size_t)(b * 2) * HWn + rem]     = oe;
    out[(size_t)(b * 2 + 1) * HWn + rem] = od;
}

extern "C" void kernel_launch(void* const* d_in, const int* in_sizes, int n_in,
                              void* d_out, int out_size, void* d_ws, size_t ws_size,
                              hipStream_t stream) {
    const float* x     = (const float*)d_in[0];
    const float* we    = (const float*)d_in[1];
    const float* wd    = (const float*)d_in[2];
    const float* bn_ge = (const float*)d_in[3];
    const float* bn_gd = (const float*)d_in[5];
    const float* conve = (const float*)d_in[7];
    const float* convd = (const float*)d_in[8];
    const float* g_e   = (const float*)d_in[9];
    const float* b_e   = (const float*)d_in[10];
    const float* g_d   = (const float*)d_in[11];
    const float* b_d   = (const float*)d_in[12];
    float* ws = (float*)d_ws;

    const size_t need4 = (size_t)(WS_SLAB + 4 * 2 * 294912) * sizeof(float); // 11.8 MB
    const size_t need2 = (size_t)(WS_SLAB + 2 * 2 * 294912) * sizeof(float); //  7.1 MB
    const int ns = (ws_size >= need4) ? 4 : (ws_size >= need2) ? 2 : 1;

    // only sum/sqs/scal need zeroing; everything else fully overwritten
    hipMemsetAsync(d_ws, 0, 772 * sizeof(float), stream);
    hipLaunchKernelGGL(k_stats, dim3(18, 512), dim3(256), 0, stream,
                       x, we, wd, ws + WS_SUM, ws + WS_SQS);
    if (ns == 4) {
        hipLaunchKernelGGL((k_reduce<4, 8>), dim3(36, 8, 8), dim3(128), 0, stream,
                           x, we, wd, ws + WS_SUM, ws + WS_SQS, bn_ge, bn_gd,
                           conve, convd, ws + WS_YE, ws + WS_YD, ws + WS_SLAB,
                           ws + WS_SCAL);
        hipLaunchKernelGGL((k_fsum<4>), dim3(1152), dim3(256), 0, stream,
                           ws + WS_SLAB, ws + WS_YE, ws + WS_YD, ws + WS_SCAL);
    } else if (ns == 2) {
        hipLaunchKernelGGL((k_reduce<2, 8>), dim3(36, 8, 4), dim3(128), 0, stream,
                           x, we, wd, ws + WS_SUM, ws + WS_SQS, bn_ge, bn_gd,
                           conve, convd, ws + WS_YE, ws + WS_YD, ws + WS_SLAB,
                           ws + WS_SCAL);
        hipLaunchKernelGGL((k_fsum<2>), dim3(1152), dim3(256), 0, stream,
                           ws + WS_SLAB, ws + WS_YE, ws + WS_YD, ws + WS_SCAL);
    } else {
        hipLaunchKernelGGL((k_reduce<1, 4>), dim3(72, 8, 2), dim3(128), 0, stream,
                           x, we, wd, ws + WS_SUM, ws + WS_SQS, bn_ge, bn_gd,
                           conve, convd, ws + WS_YE, ws + WS_YD, ws, ws + WS_SCAL);
    }
    hipLaunchKernelGGL(k_final, dim3(1152), dim3(256), 0, stream,
                       ws + WS_YE, ws + WS_YD, ws + WS_SCAL, g_e, b_e, g_d, b_d,
                       (float*)d_out);
}

// Round 6
// 280.180 us; speedup vs baseline: 1.9071x; 1.9071x over previous
//
#include <hip/hip_runtime.h>

// DEChannelPool: 6 soft-morphology branches + per-channel BN + 1x1 conv + BN + ReLU.
// Trick 1: exp(beta*(w±x)) = exp(beta*w)*exp(±beta*x): 2 exps per input pixel.
// Trick 2: BN+conv fold to alpha*log2(S) + const; const cancels in final scalar BN.
// R6: fix R5 regression. k_reduce: merged sides (one load -> two planes), 32x32
//     tiles / 256 thr / 4-row strips, launch_bounds(256,4) -- R5's (128,8) forced a
//     VGPR cap that spilled L[13] to scratch (463 MB writes + 306 MB re-reads =
//     the 324 us). Weights read via wave-uniform GLOBAL pointer (s_load path)
//     instead of LDS broadcast: -25% LDS-pipe instrs in both stencil kernels.

#define BETA 15.0f
#define MSHIFT 25.0f
#define INV_BETA (1.0f/15.0f)
#define LN2 0.6931471805599453f
#define EPSB 1e-5f
#define Hn 192
#define Wn 192
#define HWn (192*192)
#define N1 (8*192*192)
#define SFLOOR 1e-37f

// ---- stats kernel geometry: 64r x 32c tile, 8-row strips, 256 thr, BOTH sides ----
#define STDH 70
#define STW 38
#define STSTR 39            // 8*39 % 32 = 24 -> 2-way strip aliasing (free)
#define STNL (STDH*STW)     // 2660

// ---- reduce kernel geometry: 32r x 32c tile, 4-row strips, 256 thr, BOTH sides ----
#define RDH 38
#define RSTR 39             // 4*39 % 32 = 28 -> strips on 8 distinct banks, 2-way
#define RNL (RDH*STW)       // 1444
#define RNITER 6

// workspace layout (float offsets)
#define WS_SUM   0
#define WS_SQS   384
#define WS_SCAL  768
#define WS_WG    772
#define WS_YE    (772 + 3456)
#define WS_YD    (WS_YE + 294912)
#define WS_SLAB  (WS_YE + 2*294912)   // [2 sides * NS grps][8 b][HWn]

__global__ void k_wexp(const float* __restrict__ we,
                       const float* __restrict__ wd,
                       float* __restrict__ wg) {
    int idx = blockIdx.x * 256 + threadIdx.x;
    if (idx >= 3456) return;
    int kb = idx / 576;            // 0..5 = side*3+br (0-2 erosion, 3-5 dilation)
    int rem = idx - kb * 576;      // c*9 + tap
    float w = (kb < 3) ? we[kb * 576 + rem] : wd[(kb - 3) * 576 + rem];
    wg[idx] = __expf(BETA * w);
}

// Register-rotating stencil over one plane. Each b32 read feeds up to 3 of the H
// output accumulators. All offsets literal after unroll. wgp is a wave-uniform
// GLOBAL pointer -> scalar loads, keeps the LDS pipe for plane reads only.
template<int D, int H, int STR>
__device__ __forceinline__ void sweepT(const float* __restrict__ P,
                                       int py0, int px,
                                       const float* __restrict__ wgp,
                                       float* __restrict__ S) {
    float W[9];
#pragma unroll
    for (int k2 = 0; k2 < 9; ++k2) W[k2] = wgp[k2];
#pragma unroll
    for (int k = 0; k < H; ++k) S[k] = 0.f;
    const float* base = P + (py0 - D + 3) * STR + (px - D);
#pragma unroll
    for (int r = 0; r < H + 2 * D; ++r) {
        float va = base[r * STR];
        float vb = base[r * STR + D];
        float vc = base[r * STR + 2 * D];
#pragma unroll
        for (int i = 0; i < 3; ++i) {
            int k = r - i * D;            // output row fed by input row r via weight-row i
            if (k >= 0 && k < H) {
                S[k] = fmaf(W[i*3+0], va, S[k]);
                S[k] = fmaf(W[i*3+1], vb, S[k]);
                S[k] = fmaf(W[i*3+2], vc, S[k]);
            }
        }
    }
}

__device__ __forceinline__ void red2(float a, float b2, int lane, float* rs, float* rq) {
#pragma unroll
    for (int off = 32; off; off >>= 1) {
        a  += __shfl_down(a, off, 64);
        b2 += __shfl_down(b2, off, 64);
    }
    if (lane == 0) { *rs = a; *rq = b2; }
}

// grid (18 tiles, 512 b*c), 256 threads. One tile load feeds BOTH side planes.
__global__ __launch_bounds__(256, 7) void k_stats(
    const float* __restrict__ x, const float* __restrict__ wg,
    float* __restrict__ sum, float* __restrict__ sqs) {
    __shared__ float EX[STDH * STSTR], EY[STDH * STSTR];
    __shared__ float redS[4][6], redQ[4][6];
    const int tid = threadIdx.x;
    const int p = blockIdx.y;            // b*64 + c
    const int c = p & 63;
    const int t = blockIdx.x;
    const int h0 = (t / 6) * 64, w0 = (t % 6) * 32;

    const float* xp = x + (size_t)p * HWn;
    {
        int r = tid / STW, cc = tid - r * STW;
        for (int l = tid; l < STNL; l += 256) {
            int gh = h0 - 3 + r, gw = w0 - 3 + cc;
            float v = 0.f;
            if ((unsigned)gh < (unsigned)Hn && (unsigned)gw < (unsigned)Wn)
                v = xp[gh * Wn + gw];
            float bx = BETA * v;          // OOB/pad: v=0 -> exp(-M) both sides, correct
            EX[r * STSTR + cc] = __expf(-bx - MSHIFT);
            EY[r * STSTR + cc] = __expf( bx - MSHIFT);
            r += 6; cc += 28;             // 256 = 6*38 + 28
            if (cc >= STW) { cc -= STW; ++r; }
        }
    }
    __syncthreads();

    const int px = (tid & 31) + 3;
    const int py0 = (tid >> 5) * 8;
    const int lane = tid & 63, wv = tid >> 6;
    const float LI = LN2 * INV_BETA, MI = MSHIFT * INV_BETA;

#define DO_BR_STATS(D, SLOT, PL, AL, AM) { \
    float S[8]; \
    sweepT<D, 8, STSTR>(PL, py0, px, wg + (SLOT) * 576 + c * 9, S); \
    float sv = 0.f, qv = 0.f; \
    _Pragma("unroll") \
    for (int k = 0; k < 8; ++k) { \
        float m = fmaf(__log2f(fmaxf(S[k], SFLOOR)), AL, AM); \
        sv += m; qv = fmaf(m, m, qv); \
    } \
    red2(sv, qv, lane, &redS[wv][SLOT], &redQ[wv][SLOT]); }

    DO_BR_STATS(1, 0, EX, -LI, -MI)
    DO_BR_STATS(2, 1, EX, -LI, -MI)
    DO_BR_STATS(3, 2, EX, -LI, -MI)
    DO_BR_STATS(1, 3, EY,  LI,  MI)
    DO_BR_STATS(2, 4, EY,  LI,  MI)
    DO_BR_STATS(3, 5, EY,  LI,  MI)

    __syncthreads();
    if (tid < 6)
        atomicAdd(&sum[tid * 64 + c],
                  redS[0][tid] + redS[1][tid] + redS[2][tid] + redS[3][tid]);
    else if (tid < 12) {
        int v = tid - 6;
        atomicAdd(&sqs[v * 64 + c],
                  redQ[0][v] + redQ[1][v] + redQ[2][v] + redQ[3][v]);
    }
}

// grid (36 tiles, 8 b, NS grps), 256 threads. Block sweeps NC=64/NS channels,
// BOTH sides, over a 32x32 tile. One x load feeds both planes. NS>1: partials
// to slabs; NS==1: final ye/yd + scalar BN stats. alpha computed in-block.
template<int NS>
__global__ __launch_bounds__(256, 4) void k_reduce(
    const float* __restrict__ x, const float* __restrict__ wg,
    const float* __restrict__ sum, const float* __restrict__ sqs,
    const float* __restrict__ bn_ge, const float* __restrict__ bn_gd,
    const float* __restrict__ conve, const float* __restrict__ convd,
    float* __restrict__ ye, float* __restrict__ yd,
    float* __restrict__ slab, float* __restrict__ scal) {
    constexpr int NC = 64 / NS;
    __shared__ float EX[RDH * RSTR], EY[RDH * RSTR];
    __shared__ float al[384];
    __shared__ float redA[4][4];
    const int tid = threadIdx.x;
    const int t = blockIdx.x;
    const int b = blockIdx.y;
    const int grp = blockIdx.z;
    const int c0 = grp * NC;
    const int tr = t / 6, tc = t - tr * 6;
    const int h0 = tr * 32, w0 = tc * 32;
    const int px = (tid & 31) + 3;
    const int py0 = (tid >> 5) * 4;
    const float* xb = x + (size_t)b * 64 * HWn;

    // alpha for all 384 (side,br,c) slots; slot index = side*192 + br*64 + c
    for (int l = tid; l < 384; l += 256) {
        int side_ = l / 192, ch = l - side_ * 192;
        float mean = sum[l] * (1.0f / N1);
        float var  = sqs[l] * (1.0f / N1) - mean * mean;
        float inv  = rsqrtf(fmaxf(var, 0.f) + EPSB);
        float g  = side_ ? bn_gd[ch] : bn_ge[ch];
        float cw = side_ ? convd[ch] : conve[ch];
        float sgn = side_ ? 1.f : -1.f;
        al[l] = sgn * cw * g * inv * INV_BETA * LN2;
    }

    float accE[4] = {0.f, 0.f, 0.f, 0.f}, accD[4] = {0.f, 0.f, 0.f, 0.f};
    float L[RNITER];

    // prologue: prefetch channel c0 (raw x) into registers
    {
        const float* xp = xb + (size_t)c0 * HWn;
        int r = tid / STW, cc = tid - r * STW;
#pragma unroll
        for (int i = 0; i < RNITER; ++i) {
            int l = tid + i * 256;
            float v = 0.f;
            if (l < RNL) {
                int gh = h0 - 3 + r, gw = w0 - 3 + cc;
                if ((unsigned)gh < (unsigned)Hn && (unsigned)gw < (unsigned)Wn)
                    v = xp[gh * Wn + gw];
            }
            L[i] = v;
            r += 6; cc += 28;             // 256 = 6*38 + 28
            if (cc >= STW) { cc -= STW; ++r; }
        }
    }

    for (int ci = 0; ci < NC; ++ci) {
        __syncthreads();                  // planes free (iter 0: al visible)
        {   // write phase: both exps from the prefetched raw values
            int r = tid / STW, cc = tid - r * STW;
#pragma unroll
            for (int i = 0; i < RNITER; ++i) {
                int l = tid + i * 256;
                if (l < RNL) {
                    float bx = BETA * L[i];
                    EX[r * RSTR + cc] = __expf(-bx - MSHIFT);
                    EY[r * RSTR + cc] = __expf( bx - MSHIFT);
                }
                r += 6; cc += 28;
                if (cc >= STW) { cc -= STW; ++r; }
            }
        }
        __syncthreads();
        if (ci < NC - 1) {                // prefetch next channel (overlaps sweeps)
            const float* xp = xb + (size_t)(c0 + ci + 1) * HWn;
            int r = tid / STW, cc = tid - r * STW;
#pragma unroll
            for (int i = 0; i < RNITER; ++i) {
                int l = tid + i * 256;
                float v = 0.f;
                if (l < RNL) {
                    int gh = h0 - 3 + r, gw = w0 - 3 + cc;
                    if ((unsigned)gh < (unsigned)Hn && (unsigned)gw < (unsigned)Wn)
                        v = xp[gh * Wn + gw];
                }
                L[i] = v;
                r += 6; cc += 28;
                if (cc >= STW) { cc -= STW; ++r; }
            }
        }
        const int c = c0 + ci;
#define DO_BR_ACC(D, SIDE, BR, PL, ACC) { \
        float S[4]; \
        sweepT<D, 4, RSTR>(PL, py0, px, wg + ((SIDE) * 3 + (BR)) * 576 + c * 9, S); \
        const float a_ = al[(SIDE) * 192 + (BR) * 64 + c]; \
        _Pragma("unroll") \
        for (int k = 0; k < 4; ++k) \
            ACC[k] = fmaf(a_, __log2f(fmaxf(S[k], SFLOOR)), ACC[k]); }

        DO_BR_ACC(1, 0, 0, EX, accE)
        DO_BR_ACC(2, 0, 1, EX, accE)
        DO_BR_ACC(3, 0, 2, EX, accE)
        DO_BR_ACC(1, 1, 0, EY, accD)
        DO_BR_ACC(2, 1, 1, EY, accD)
        DO_BR_ACC(3, 1, 2, EY, accD)
    }

    if constexpr (NS == 1) {
        const int oidx = b * HWn + (h0 + py0) * Wn + (w0 + px - 3);
#pragma unroll
        for (int k = 0; k < 4; ++k) {
            ye[oidx + k * Wn] = accE[k];
            yd[oidx + k * Wn] = accD[k];
        }
        float se = 0.f, qe = 0.f, sd = 0.f, qd = 0.f;
#pragma unroll
        for (int k = 0; k < 4; ++k) {
            se += accE[k]; qe = fmaf(accE[k], accE[k], qe);
            sd += accD[k]; qd = fmaf(accD[k], accD[k], qd);
        }
        const int lane = tid & 63, wv = tid >> 6;
        float v4[4] = {se, qe, sd, qd};
#pragma unroll
        for (int j = 0; j < 4; ++j) {
            float tv = v4[j];
#pragma unroll
            for (int off = 32; off; off >>= 1) tv += __shfl_down(tv, off, 64);
            if (lane == 0) redA[wv][j] = tv;
        }
        __syncthreads();
        if (tid < 4)
            atomicAdd(&scal[tid],
                      redA[0][tid] + redA[1][tid] + redA[2][tid] + redA[3][tid]);
    } else {
        float* pe = slab + ((size_t)grp * 8 + b) * HWn;
        float* pd = slab + ((size_t)(NS + grp) * 8 + b) * HWn;
        const int oidx = (h0 + py0) * Wn + (w0 + px - 3);
#pragma unroll
        for (int k = 0; k < 4; ++k) {
            pe[oidx + k * Wn] = accE[k];
            pd[oidx + k * Wn] = accD[k];
        }
    }
}

// NS>1 path: sum the NS chunk partials per pixel -> ye/yd + scalar BN stats.
template<int NS>
__global__ __launch_bounds__(256) void k_fsum(
    const float* __restrict__ slab,
    float* __restrict__ ye, float* __restrict__ yd, float* __restrict__ scal) {
    int i = blockIdx.x * 256 + threadIdx.x;   // < 294912
    int b = i / HWn, rem = i - b * HWn;
    float e = 0.f, d = 0.f;
#pragma unroll
    for (int g = 0; g < NS; ++g) {
        e += slab[((size_t)g * 8 + b) * HWn + rem];
        d += slab[((size_t)(NS + g) * 8 + b) * HWn + rem];
    }
    ye[i] = e; yd[i] = d;
    float v[4] = {e, e * e, d, d * d};
    __shared__ float red[4][4];
    int lane = threadIdx.x & 63, wv = threadIdx.x >> 6;
#pragma unroll
    for (int k = 0; k < 4; ++k) {
        float tv = v[k];
#pragma unroll
        for (int off = 32; off; off >>= 1) tv += __shfl_down(tv, off, 64);
        if (lane == 0) red[wv][k] = tv;
    }
    __syncthreads();
    if (threadIdx.x < 4)
        atomicAdd(&scal[threadIdx.x],
                  red[0][threadIdx.x] + red[1][threadIdx.x] + red[2][threadIdx.x] + red[3][threadIdx.x]);
}

__global__ __launch_bounds__(256) void k_final(
    const float* __restrict__ ye, const float* __restrict__ yd,
    const float* __restrict__ scal,
    const float* __restrict__ g_e, const float* __restrict__ b_e,
    const float* __restrict__ g_d, const float* __restrict__ b_d,
    float* __restrict__ out) {
    int i = blockIdx.x * 256 + threadIdx.x;  // < 294912
    float me_ = scal[0] * (1.0f / N1);
    float ve  = scal[1] * (1.0f / N1) - me_ * me_;
    float ie  = rsqrtf(fmaxf(ve, 0.f) + EPSB);
    float md_ = scal[2] * (1.0f / N1);
    float vd  = scal[3] * (1.0f / N1) - md_ * md_;
    float idv = rsqrtf(fmaxf(vd, 0.f) + EPSB);
    float ge = g_e[0], be = b_e[0];
    float gd = g_d[0], bd = b_d[0];
    int b = i / HWn, rem = i - b * HWn;
    float oe = fmaxf(ge * (ye[i] - me_) * ie + be, 0.f);
    float od = fmaxf(gd * (yd[i] - md_) * idv + bd, 0.f);
    out[(size_t)(b * 2) * HWn + rem]     = oe;
    out[(size_t)(b * 2 + 1) * HWn + rem] = od;
}

extern "C" void kernel_launch(void* const* d_in, const int* in_sizes, int n_in,
                              void* d_out, int out_size, void* d_ws, size_t ws_size,
                              hipStream_t stream) {
    const float* x     = (const float*)d_in[0];
    const float* we    = (const float*)d_in[1];
    const float* wd    = (const float*)d_in[2];
    const float* bn_ge = (const float*)d_in[3];
    const float* bn_gd = (const float*)d_in[5];
    const float* conve = (const float*)d_in[7];
    const float* convd = (const float*)d_in[8];
    const float* g_e   = (const float*)d_in[9];
    const float* b_e   = (const float*)d_in[10];
    const float* g_d   = (const float*)d_in[11];
    const float* b_d   = (const float*)d_in[12];
    float* ws = (float*)d_ws;

    const size_t need4 = (size_t)(WS_SLAB + 4 * 2 * 294912) * sizeof(float); // 11.8 MB
    const size_t need2 = (size_t)(WS_SLAB + 2 * 2 * 294912) * sizeof(float); //  7.1 MB
    const int ns = (ws_size >= need4) ? 4 : (ws_size >= need2) ? 2 : 1;

    // only sum/sqs/scal need zeroing; everything else fully overwritten
    hipMemsetAsync(d_ws, 0, 772 * sizeof(float), stream);
    hipLaunchKernelGGL(k_wexp, dim3(14), dim3(256), 0, stream, we, wd, ws + WS_WG);
    hipLaunchKernelGGL(k_stats, dim3(18, 512), dim3(256), 0, stream,
                       x, ws + WS_WG, ws + WS_SUM, ws + WS_SQS);
    if (ns == 4) {
        hipLaunchKernelGGL((k_reduce<4>), dim3(36, 8, 4), dim3(256), 0, stream,
                           x, ws + WS_WG, ws + WS_SUM, ws + WS_SQS, bn_ge, bn_gd,
                           conve, convd, ws + WS_YE, ws + WS_YD, ws + WS_SLAB,
                           ws + WS_SCAL);
        hipLaunchKernelGGL((k_fsum<4>), dim3(1152), dim3(256), 0, stream,
                           ws + WS_SLAB, ws + WS_YE, ws + WS_YD, ws + WS_SCAL);
    } else if (ns == 2) {
        hipLaunchKernelGGL((k_reduce<2>), dim3(36, 8, 2), dim3(256), 0, stream,
                           x, ws + WS_WG, ws + WS_SUM, ws + WS_SQS, bn_ge, bn_gd,
                           conve, convd, ws + WS_YE, ws + WS_YD, ws + WS_SLAB,
                           ws + WS_SCAL);
        hipLaunchKernelGGL((k_fsum<2>), dim3(1152), dim3(256), 0, stream,
                           ws + WS_SLAB, ws + WS_YE, ws + WS_YD, ws + WS_SCAL);
    } else {
        hipLaunchKernelGGL((k_reduce<1>), dim3(36, 8, 1), dim3(256), 0, stream,
                           x, ws + WS_WG, ws + WS_SUM, ws + WS_SQS, bn_ge, bn_gd,
                           conve, convd, ws + WS_YE, ws + WS_YD, ws, ws + WS_SCAL);
    }
    hipLaunchKernelGGL(k_final, dim3(1152), dim3(256), 0, stream,
                       ws + WS_YE, ws + WS_YD, ws + WS_SCAL, g_e, b_e, g_d, b_d,
                       (float*)d_out);
}